// Round 16
// baseline (53.583 us; speedup 1.0000x reference)
//
#include <hip/hip_runtime.h>

typedef _Float16 f16x8 __attribute__((ext_vector_type(8)));
typedef __fp16   h16x2 __attribute__((ext_vector_type(2)));
typedef float    f32x4 __attribute__((ext_vector_type(4)));
typedef uint     u32x4 __attribute__((ext_vector_type(4)));

#define NB   8
#define CIN  256
#define CC   512
#define SS   1024
#define NH   8
#define DH   64

#define SCL 0.18033688f   // 0.125 * log2(e), folded into Wq/bq
#define THR 11.5409f      // 8 nats in log2 units

static __device__ __forceinline__ ushort f2h(float f) {
  union { _Float16 h; ushort u; } cv;
  cv.h = (_Float16)f;
  return cv.u;
}
static __device__ __forceinline__ uint pk2u(float a, float b) {
  union { h16x2 h; uint u; } cv;
  cv.h = __builtin_amdgcn_cvt_pkrtz(a, b);
  return cv.u;
}

// ---------------------------------------------------------------------------
// Kernel 1: prep = xpose (blocks 0..1023) + wnorm (blocks 1024..2559).
// ---------------------------------------------------------------------------
__global__ __launch_bounds__(256)
void prep_kernel(const float* __restrict__ query, const float* __restrict__ key,
                 const float* __restrict__ vq, const float* __restrict__ gq,
                 const float* __restrict__ vk, const float* __restrict__ gk,
                 const float* __restrict__ vv, const float* __restrict__ gv,
                 ushort* __restrict__ Xt, ushort* __restrict__ w_all) {
  const int t = threadIdx.x;
  __shared__ float T[64 * 64];

  if (blockIdx.x < 1024) {
    const int bx = blockIdx.x;
    const int kt = bx & 3, st = (bx >> 2) & 15, b = (bx >> 6) & 7, mat = bx >> 9;
    const float* Xf = ((mat == 0) ? query : key)
                      + (size_t)b * CIN * SS + (size_t)(kt * 64) * SS + st * 64;
    ushort* Ot = Xt + ((size_t)(mat * NB + b) * SS + st * 64) * CIN + kt * 64;

    const int kl0 = t >> 4;          // 0..15
    const int s4  = (t & 15) * 4;
    #pragma unroll
    for (int p = 0; p < 4; p++) {
      const int kl = p * 16 + kl0;
      const float4 xv = *(const float4*)&Xf[(size_t)kl * SS + s4];
      T[(s4 + 0) * 64 + (kl ^ (s4 + 0))] = xv.x;
      T[(s4 + 1) * 64 + (kl ^ (s4 + 1))] = xv.y;
      T[(s4 + 2) * 64 + (kl ^ (s4 + 2))] = xv.z;
      T[(s4 + 3) * 64 + (kl ^ (s4 + 3))] = xv.w;
    }
    __syncthreads();

    const int sl = t >> 2;           // 0..63
    const int k0 = (t & 3) * 16;
    uint ow[8];
    #pragma unroll
    for (int q = 0; q < 8; q++) {
      const float f0 = T[sl * 64 + ((k0 + 2 * q) ^ sl)];
      const float f1 = T[sl * 64 + ((k0 + 2 * q + 1) ^ sl)];
      ow[q] = pk2u(f0, f1);
    }
    *(u32x4*)&Ot[(size_t)sl * CIN + k0]     = (u32x4){ow[0], ow[1], ow[2], ow[3]};
    *(u32x4*)&Ot[(size_t)sl * CIN + k0 + 8] = (u32x4){ow[4], ow[5], ow[6], ow[7]};
  } else {
    const int idx = blockIdx.x - 1024;      // 0..1535
    const int mat = idx >> 9, c = idx & 511;
    const float* v = (mat == 0) ? vq : (mat == 1) ? vk : vv;
    const float* g = (mat == 0) ? gq : (mat == 1) ? gk : gv;

    float val = v[c * CIN + t];
    float s = val * val;
    #pragma unroll
    for (int off = 32; off; off >>= 1) s += __shfl_down(s, off);

    const int wave = t >> 6;
    if ((t & 63) == 0) T[wave] = s;
    __syncthreads();
    float tot = T[0] + T[1] + T[2] + T[3];
    float scale = g[c] * rsqrtf(tot);
    if (mat == 0) scale *= SCL;
    w_all[(size_t)mat * CC * CIN + c * CIN + t] = f2h(val * scale);
  }
}

// ---------------------------------------------------------------------------
// Kernel 2: projection GEMM, both operands k-contiguous f16 (round-8 proven
// version: reg-staged, scalar lane-contiguous epilogue stores).
// ---------------------------------------------------------------------------
__global__ __launch_bounds__(256)
void proj_kernel(const ushort* __restrict__ Xt, const ushort* __restrict__ w_all,
                 const float* __restrict__ bq, const float* __restrict__ bk,
                 const float* __restrict__ bv,
                 ushort* __restrict__ qkv) {
  const int wg  = blockIdx.x;                       // 0..767
  const int swb = (wg & 7) * 96 + (wg >> 3);        // bijective XCD swizzle
  const int tn = swb & 3, tm = (swb >> 2) & 7;
  const int b  = (swb >> 5) & 7, mz = swb >> 8;
  const int t  = threadIdx.x;
  const int s0 = tm * 128, c0 = tn * 128;

  const ushort* Xb = Xt + ((size_t)(((mz == 0) ? 0 : NB) + b) * SS + s0) * CIN;
  const ushort* Wb = w_all + (size_t)mz * CC * CIN + (size_t)c0 * CIN;
  const float*  bias = (mz == 0) ? bq : (mz == 1) ? bk : bv;
  const float   bscale = (mz == 0) ? SCL : 1.f;
  ushort*       outp = qkv + (size_t)mz * NB * NH * SS * DH;

  __shared__ __align__(16) ushort Xs[128 * 64];
  __shared__ __align__(16) ushort Ws[128 * 64];

  const int wave = t >> 6, lane = t & 63;
  const int wm = wave >> 1, wn = wave & 1;
  const int lrow = lane & 15, kg = lane >> 4;

  const int srow = t >> 3;         // 0..31
  const int scol = (t & 7) * 8;

  f16x8 xr[4], wr[4];
  auto LOADT = [&](int kt) {
    const int k0 = kt * 64;
    #pragma unroll
    for (int q = 0; q < 4; q++) {
      const int row = q * 32 + srow;
      xr[q] = *(const f16x8*)&Xb[(size_t)row * CIN + k0 + scol];
      wr[q] = *(const f16x8*)&Wb[(size_t)row * CIN + k0 + scol];
    }
  };
  auto STORET = [&]() {
    #pragma unroll
    for (int q = 0; q < 4; q++) {
      const int row = q * 32 + srow;
      const int off = row * 64 + (scol ^ (8 * (row & 7)));
      *(f16x8*)&Xs[off] = xr[q];
      *(f16x8*)&Ws[off] = wr[q];
    }
  };

  f32x4 acc[4][4];
  #pragma unroll
  for (int i = 0; i < 4; i++)
    #pragma unroll
    for (int j = 0; j < 4; j++) acc[i][j] = (f32x4){0.f, 0.f, 0.f, 0.f};

  LOADT(0);
  STORET();
  LOADT(1);
  __syncthreads();

  const int swzA = 8 * (lrow & 7);
  for (int kt = 0; kt < 4; ++kt) {
    f16x8 a[4][2], bf[4][2];
    #pragma unroll
    for (int i = 0; i < 4; i++) {
      const int ra = (wm * 64 + i * 16 + lrow) * 64;
      a[i][0] = *(const f16x8*)&Xs[ra + ((kg * 8) ^ swzA)];
      a[i][1] = *(const f16x8*)&Xs[ra + ((32 + kg * 8) ^ swzA)];
      const int rb = (wn * 64 + i * 16 + lrow) * 64;
      bf[i][0] = *(const f16x8*)&Ws[rb + ((kg * 8) ^ swzA)];
      bf[i][1] = *(const f16x8*)&Ws[rb + ((32 + kg * 8) ^ swzA)];
    }
    if (mz == 2) {
      #pragma unroll
      for (int i = 0; i < 4; i++)
        #pragma unroll
        for (int j = 0; j < 4; j++) {
          acc[i][j] = __builtin_amdgcn_mfma_f32_16x16x32_f16(bf[j][0], a[i][0], acc[i][j], 0, 0, 0);
          acc[i][j] = __builtin_amdgcn_mfma_f32_16x16x32_f16(bf[j][1], a[i][1], acc[i][j], 0, 0, 0);
        }
    } else {
      #pragma unroll
      for (int i = 0; i < 4; i++)
        #pragma unroll
        for (int j = 0; j < 4; j++) {
          acc[i][j] = __builtin_amdgcn_mfma_f32_16x16x32_f16(a[i][0], bf[j][0], acc[i][j], 0, 0, 0);
          acc[i][j] = __builtin_amdgcn_mfma_f32_16x16x32_f16(a[i][1], bf[j][1], acc[i][j], 0, 0, 0);
        }
    }
    if (kt < 3) {
      __syncthreads();
      STORET();
      if (kt < 2) LOADT(kt + 2);
      __syncthreads();
    }
  }

  if (mz == 2) {
    #pragma unroll
    for (int i = 0; i < 4; i++) {
      const int sg = s0 + wm * 64 + i * 16 + lrow;
      #pragma unroll
      for (int j = 0; j < 4; j++) {
        #pragma unroll
        for (int r = 0; r < 4; r++) {
          const int c = c0 + wn * 64 + j * 16 + kg * 4 + r;
          outp[(((size_t)b * NH + (c >> 6)) * DH + (c & 63)) * SS + sg] =
              f2h(acc[i][j][r] + bias[c]);
        }
      }
    }
  } else {
    #pragma unroll
    for (int i = 0; i < 4; i++) {
      const int srw = s0 + wm * 64 + i * 16 + kg * 4;
      #pragma unroll
      for (int j = 0; j < 4; j++) {
        const int cgl = c0 + wn * 64 + j * 16 + lrow;
        const float bias_c = bias[cgl] * bscale;
        const size_t obase = (((size_t)b * NH + (cgl >> 6)) * SS) * DH + (cgl & 63);
        #pragma unroll
        for (int r = 0; r < 4; r++)
          outp[obase + (size_t)(srw + r) * DH] = f2h(acc[i][j][r] + bias_c);
      }
    }
  }
}

// ---------------------------------------------------------------------------
// Kernel 3: causal flash attention (round-12 measured-best structure +
// s_setprio(1) around the two MFMA clusters — T5 isolated test; waves on a
// SIMD come from 4 independent blocks at different tiles = role diversity).
// ---------------------------------------------------------------------------
__global__ __launch_bounds__(256, 4)
void attn_kernel(const ushort* __restrict__ Q, const ushort* __restrict__ K,
                 const ushort* __restrict__ V, float* __restrict__ out) {
  const int wg = blockIdx.x;                   // 0..1023
  const int j  = wg >> 3;
  const int r  = j & 15, s = j >> 4;
  const int qt = ((s >> 1) & 1) ? (15 - r) : r;
  const int bh = (wg & 7) * 8 + s;
  const int nt = qt + 1;
  const int t = threadIdx.x;
  const int wave = t >> 6, lane = t & 63;
  const int lrow = lane & 15, kg = lane >> 4;

  __shared__ __align__(16) ushort Ks[2][64 * 64];
  __shared__ __align__(16) ushort Vs[2][64 * 64];

  const ushort* Qb = Q + (size_t)bh * SS * DH;
  const ushort* Kb = K + (size_t)bh * SS * DH;   // [s][d]
  const ushort* Vb = V + (size_t)bh * DH * SS;   // [d][s]

  const int qg = qt * 64 + wave * 16 + lrow;

  f16x8 qa0 = *(const f16x8*)&Qb[(size_t)qg * DH + kg * 8];
  f16x8 qa1 = *(const f16x8*)&Qb[(size_t)qg * DH + 32 + kg * 8];

  float m = -1e30f, l = 0.f;
  f32x4 o[4];
  #pragma unroll
  for (int d = 0; d < 4; d++) o[d] = (f32x4){0.f, 0.f, 0.f, 0.f};

  const int r0 = t >> 3,        c0s = (t & 7) * 8;
  const int r1 = 32 + (t >> 3), c1s = c0s;
  const int ke0 = r0 * 64 + (c0s ^ (8 * (r0 & 7)));
  const int ke1 = r1 * 64 + (c1s ^ (8 * (r1 & 7)));

  f16x8 kr0, kr1, vr0, vr1;
  auto LOADT = [&](int jt) {
    const int j0 = jt * 64;
    kr0 = *(const f16x8*)&Kb[(size_t)(j0 + r0) * DH + c0s];
    kr1 = *(const f16x8*)&Kb[(size_t)(j0 + r1) * DH + c1s];
    vr0 = *(const f16x8*)&Vb[(size_t)r0 * SS + j0 + c0s];
    vr1 = *(const f16x8*)&Vb[(size_t)r1 * SS + j0 + c1s];
  };
  auto STORET = [&](int buf) {
    *(f16x8*)&Ks[buf][ke0] = kr0;
    *(f16x8*)&Ks[buf][ke1] = kr1;
    *(f16x8*)&Vs[buf][ke0] = vr0;
    *(f16x8*)&Vs[buf][ke1] = vr1;
  };

  LOADT(0);
  STORET(0);
  if (nt > 1) LOADT(1);
  __syncthreads();

  const int swz = 8 * (lrow & 7);

  for (int jt = 0; jt < nt; ++jt) {
    const int cur = jt & 1;
    const ushort* Kc = Ks[cur];
    const ushort* Vc = Vs[cur];
    const int j0 = jt * 64;
    const bool diag = (jt == qt);

    // S^T = K·Q^T  (z[cf][r] = score[key j0+cf*16+kg*4+r][q = qg], log2 dom)
    f32x4 z[4];
    #pragma unroll
    for (int cf = 0; cf < 4; cf++) z[cf] = (f32x4){0.f, 0.f, 0.f, 0.f};
    __builtin_amdgcn_s_setprio(1);
    #pragma unroll
    for (int cf = 0; cf < 4; ++cf) {
      const int krow = (cf * 16 + lrow) * 64;
      f16x8 ka0 = *(const f16x8*)&Kc[krow + ((kg * 8) ^ swz)];
      f16x8 ka1 = *(const f16x8*)&Kc[krow + ((32 + kg * 8) ^ swz)];
      z[cf] = __builtin_amdgcn_mfma_f32_16x16x32_f16(ka0, qa0, z[cf], 0, 0, 0);
      z[cf] = __builtin_amdgcn_mfma_f32_16x16x32_f16(ka1, qa1, z[cf], 0, 0, 0);
    }
    __builtin_amdgcn_s_setprio(0);

    if (diag) {
      #pragma unroll
      for (int cf = 0; cf < 4; cf++)
        #pragma unroll
        for (int rr = 0; rr < 4; rr++) {
          const int keyi = j0 + cf * 16 + kg * 4 + rr;
          if (keyi >= qg) z[cf][rr] = -1e9f;
        }
    }
    // lane-local max; full cross-lane reduce only inside the rescale branch
    float mxl = z[0][0];
    #pragma unroll
    for (int cf = 0; cf < 4; cf++)
      #pragma unroll
      for (int rr = 0; rr < 4; rr++) mxl = fmaxf(mxl, z[cf][rr]);
    if (__any(mxl > m + THR)) {
      float mx = fmaxf(mxl, __shfl_xor(mxl, 16));
      mx = fmaxf(mx, __shfl_xor(mx, 32));
      const float mn = fmaxf(m, mx);
      const float corr = exp2f(m - mn);
      m = mn;
      l *= corr;
      #pragma unroll
      for (int d = 0; d < 4; d++) o[d] *= corr;
    }
    float ps = 0.f;
    #pragma unroll
    for (int cf = 0; cf < 4; cf++)
      #pragma unroll
      for (int rr = 0; rr < 4; rr++) {
        z[cf][rr] = exp2f(z[cf][rr] - m);
        ps += z[cf][rr];
      }
    ps += __shfl_xor(ps, 16);
    ps += __shfl_xor(ps, 32);
    l += ps;

    // In-register P redistribution (4-lane kg butterfly).
    uint u0 = pk2u(z[0][0], z[0][1]), u1 = pk2u(z[0][2], z[0][3]);
    uint u2 = pk2u(z[1][0], z[1][1]), u3 = pk2u(z[1][2], z[1][3]);
    uint u4 = pk2u(z[2][0], z[2][1]), u5 = pk2u(z[2][2], z[2][3]);
    uint u6 = pk2u(z[3][0], z[3][1]), u7 = pk2u(z[3][2], z[3][3]);
    const bool hi2 = (kg & 2) != 0;
    uint tA0 = hi2 ? u0 : u2, tA1 = hi2 ? u1 : u3;
    uint tA2 = hi2 ? u4 : u6, tA3 = hi2 ? u5 : u7;
    uint rA0 = __shfl_xor((int)tA0, 32), rA1 = __shfl_xor((int)tA1, 32);
    uint rA2 = __shfl_xor((int)tA2, 32), rA3 = __shfl_xor((int)tA3, 32);
    const bool sel = ((kg ^ (kg >> 1)) & 1) != 0;
    uint oc0 = hi2 ? u2 : u0, oc1 = hi2 ? u3 : u1;
    uint oc2 = hi2 ? u6 : u4, oc3 = hi2 ? u7 : u5;
    uint sB0 = sel ? oc0 : rA0, sB1 = sel ? oc1 : rA1;
    uint sB2 = sel ? oc2 : rA2, sB3 = sel ? oc3 : rA3;
    uint rB0 = __shfl_xor((int)sB0, 16), rB1 = __shfl_xor((int)sB1, 16);
    uint rB2 = __shfl_xor((int)sB2, 16), rB3 = __shfl_xor((int)sB3, 16);
    uint w0 = (kg == 0) ? u0 : ((kg == 2) ? rA0 : rB0);
    uint w1 = (kg == 0) ? u1 : ((kg == 2) ? rA1 : rB1);
    uint w2 = (kg == 3) ? u2 : ((kg == 1) ? rA0 : rB0);
    uint w3 = (kg == 3) ? u3 : ((kg == 1) ? rA1 : rB1);
    uint w4 = (kg == 0) ? u4 : ((kg == 2) ? rA2 : rB2);
    uint w5 = (kg == 0) ? u5 : ((kg == 2) ? rA3 : rB3);
    uint w6 = (kg == 3) ? u6 : ((kg == 1) ? rA2 : rB2);
    uint w7 = (kg == 3) ? u7 : ((kg == 1) ? rA3 : rB3);
    union { u32x4 u; f16x8 h; } pa0v, pa1v;
    pa0v.u = (u32x4){w0, w1, w2, w3};
    pa1v.u = (u32x4){w4, w5, w6, w7};

    // O^T += V^T · P^T
    __builtin_amdgcn_s_setprio(1);
    #pragma unroll
    for (int dt = 0; dt < 4; ++dt) {
      const int vrow = (dt * 16 + lrow) * 64;
      f16x8 va0 = *(const f16x8*)&Vc[vrow + ((kg * 8) ^ swz)];
      f16x8 va1 = *(const f16x8*)&Vc[vrow + ((32 + kg * 8) ^ swz)];
      o[dt] = __builtin_amdgcn_mfma_f32_16x16x32_f16(va0, pa0v.h, o[dt], 0, 0, 0);
      o[dt] = __builtin_amdgcn_mfma_f32_16x16x32_f16(va1, pa1v.h, o[dt], 0, 0, 0);
    }
    __builtin_amdgcn_s_setprio(0);

    if (jt + 1 < nt) {
      STORET(cur ^ 1);
      if (jt + 2 < nt) LOADT(jt + 2);
      __syncthreads();
    }
  }

  const int b = bh >> 3, h = bh & 7;
  float* ob = out + ((size_t)b * CC + h * DH) * SS;
  float inv = (l > 0.f) ? 1.f / l : 0.f;
  if (qg == 0) inv = 0.f;            // start_mask: row 0 has no valid keys
  #pragma unroll
  for (int dt = 0; dt < 4; dt++)
    #pragma unroll
    for (int rr = 0; rr < 4; rr++)
      ob[(size_t)(dt * 16 + kg * 4 + rr) * SS + qg] = o[dt][rr] * inv;
}

// ---------------------------------------------------------------------------
extern "C" void kernel_launch(void* const* d_in, const int* in_sizes, int n_in,
                              void* d_out, int out_size, void* d_ws, size_t ws_size,
                              hipStream_t stream) {
  const float* query = (const float*)d_in[0];
  const float* key   = (const float*)d_in[1];
  const float* vq = (const float*)d_in[2];
  const float* gq = (const float*)d_in[3];
  const float* bq = (const float*)d_in[4];
  const float* vk = (const float*)d_in[5];
  const float* gk = (const float*)d_in[6];
  const float* bk = (const float*)d_in[7];
  const float* vv = (const float*)d_in[8];
  const float* gv = (const float*)d_in[9];
  const float* bv = (const float*)d_in[10];
  float* out = (float*)d_out;

  ushort* w_all = (ushort*)d_ws;                                   // [3][512][256] f16
  ushort* qkv   = w_all + (size_t)3 * CC * CIN;
  ushort* Xt    = qkv + (size_t)3 * NB * NH * SS * DH;             // [2][B][S][K] f16
  ushort* qb  = qkv;
  ushort* kb2 = qkv + (size_t)NB * NH * SS * DH;
  ushort* vb2 = kb2 + (size_t)NB * NH * SS * DH;                   // [b][h][d][s]

  prep_kernel<<<2560, 256, 0, stream>>>(query, key, vq, gq, vk, gk, vv, gv, Xt, w_all);
  proj_kernel<<<768, 256, 0, stream>>>(Xt, w_all, bq, bk, bv, qkv);
  attn_kernel<<<1024, 256, 0, stream>>>(qb, kb2, vb2, out);
}

// Round 17
// 53.351 us; speedup vs baseline: 1.0043x; 1.0043x over previous
//
#include <hip/hip_runtime.h>

typedef _Float16 f16x8 __attribute__((ext_vector_type(8)));
typedef __fp16   h16x2 __attribute__((ext_vector_type(2)));
typedef float    f32x4 __attribute__((ext_vector_type(4)));
typedef uint     u32x4 __attribute__((ext_vector_type(4)));

#define NB   8
#define CIN  256
#define CC   512
#define SS   1024
#define NH   8
#define DH   64

#define SCL 0.18033688f   // 0.125 * log2(e), folded into Wq/bq
#define THR 11.5409f      // 8 nats in log2 units

static __device__ __forceinline__ ushort f2h(float f) {
  union { _Float16 h; ushort u; } cv;
  cv.h = (_Float16)f;
  return cv.u;
}
static __device__ __forceinline__ uint pk2u(float a, float b) {
  union { h16x2 h; uint u; } cv;
  cv.h = __builtin_amdgcn_cvt_pkrtz(a, b);
  return cv.u;
}

// ---------------------------------------------------------------------------
// Kernel 1: prep = xpose (blocks 0..1023) + wnorm (blocks 1024..2559).
// ---------------------------------------------------------------------------
__global__ __launch_bounds__(256)
void prep_kernel(const float* __restrict__ query, const float* __restrict__ key,
                 const float* __restrict__ vq, const float* __restrict__ gq,
                 const float* __restrict__ vk, const float* __restrict__ gk,
                 const float* __restrict__ vv, const float* __restrict__ gv,
                 ushort* __restrict__ Xt, ushort* __restrict__ w_all) {
  const int t = threadIdx.x;
  __shared__ float T[64 * 64];

  if (blockIdx.x < 1024) {
    const int bx = blockIdx.x;
    const int kt = bx & 3, st = (bx >> 2) & 15, b = (bx >> 6) & 7, mat = bx >> 9;
    const float* Xf = ((mat == 0) ? query : key)
                      + (size_t)b * CIN * SS + (size_t)(kt * 64) * SS + st * 64;
    ushort* Ot = Xt + ((size_t)(mat * NB + b) * SS + st * 64) * CIN + kt * 64;

    const int kl0 = t >> 4;          // 0..15
    const int s4  = (t & 15) * 4;
    #pragma unroll
    for (int p = 0; p < 4; p++) {
      const int kl = p * 16 + kl0;
      const float4 xv = *(const float4*)&Xf[(size_t)kl * SS + s4];
      T[(s4 + 0) * 64 + (kl ^ (s4 + 0))] = xv.x;
      T[(s4 + 1) * 64 + (kl ^ (s4 + 1))] = xv.y;
      T[(s4 + 2) * 64 + (kl ^ (s4 + 2))] = xv.z;
      T[(s4 + 3) * 64 + (kl ^ (s4 + 3))] = xv.w;
    }
    __syncthreads();

    const int sl = t >> 2;           // 0..63
    const int k0 = (t & 3) * 16;
    uint ow[8];
    #pragma unroll
    for (int q = 0; q < 8; q++) {
      const float f0 = T[sl * 64 + ((k0 + 2 * q) ^ sl)];
      const float f1 = T[sl * 64 + ((k0 + 2 * q + 1) ^ sl)];
      ow[q] = pk2u(f0, f1);
    }
    *(u32x4*)&Ot[(size_t)sl * CIN + k0]     = (u32x4){ow[0], ow[1], ow[2], ow[3]};
    *(u32x4*)&Ot[(size_t)sl * CIN + k0 + 8] = (u32x4){ow[4], ow[5], ow[6], ow[7]};
  } else {
    const int idx = blockIdx.x - 1024;      // 0..1535
    const int mat = idx >> 9, c = idx & 511;
    const float* v = (mat == 0) ? vq : (mat == 1) ? vk : vv;
    const float* g = (mat == 0) ? gq : (mat == 1) ? gk : gv;

    float val = v[c * CIN + t];
    float s = val * val;
    #pragma unroll
    for (int off = 32; off; off >>= 1) s += __shfl_down(s, off);

    const int wave = t >> 6;
    if ((t & 63) == 0) T[wave] = s;
    __syncthreads();
    float tot = T[0] + T[1] + T[2] + T[3];
    float scale = g[c] * rsqrtf(tot);
    if (mat == 0) scale *= SCL;
    w_all[(size_t)mat * CC * CIN + c * CIN + t] = f2h(val * scale);
  }
}

// ---------------------------------------------------------------------------
// Kernel 2: projection GEMM, both operands k-contiguous f16 (round-8 proven
// version: reg-staged, scalar lane-contiguous epilogue stores).
// ---------------------------------------------------------------------------
__global__ __launch_bounds__(256)
void proj_kernel(const ushort* __restrict__ Xt, const ushort* __restrict__ w_all,
                 const float* __restrict__ bq, const float* __restrict__ bk,
                 const float* __restrict__ bv,
                 ushort* __restrict__ qkv) {
  const int wg  = blockIdx.x;                       // 0..767
  const int swb = (wg & 7) * 96 + (wg >> 3);        // bijective XCD swizzle
  const int tn = swb & 3, tm = (swb >> 2) & 7;
  const int b  = (swb >> 5) & 7, mz = swb >> 8;
  const int t  = threadIdx.x;
  const int s0 = tm * 128, c0 = tn * 128;

  const ushort* Xb = Xt + ((size_t)(((mz == 0) ? 0 : NB) + b) * SS + s0) * CIN;
  const ushort* Wb = w_all + (size_t)mz * CC * CIN + (size_t)c0 * CIN;
  const float*  bias = (mz == 0) ? bq : (mz == 1) ? bk : bv;
  const float   bscale = (mz == 0) ? SCL : 1.f;
  ushort*       outp = qkv + (size_t)mz * NB * NH * SS * DH;

  __shared__ __align__(16) ushort Xs[128 * 64];
  __shared__ __align__(16) ushort Ws[128 * 64];

  const int wave = t >> 6, lane = t & 63;
  const int wm = wave >> 1, wn = wave & 1;
  const int lrow = lane & 15, kg = lane >> 4;

  const int srow = t >> 3;         // 0..31
  const int scol = (t & 7) * 8;

  f16x8 xr[4], wr[4];
  auto LOADT = [&](int kt) {
    const int k0 = kt * 64;
    #pragma unroll
    for (int q = 0; q < 4; q++) {
      const int row = q * 32 + srow;
      xr[q] = *(const f16x8*)&Xb[(size_t)row * CIN + k0 + scol];
      wr[q] = *(const f16x8*)&Wb[(size_t)row * CIN + k0 + scol];
    }
  };
  auto STORET = [&]() {
    #pragma unroll
    for (int q = 0; q < 4; q++) {
      const int row = q * 32 + srow;
      const int off = row * 64 + (scol ^ (8 * (row & 7)));
      *(f16x8*)&Xs[off] = xr[q];
      *(f16x8*)&Ws[off] = wr[q];
    }
  };

  f32x4 acc[4][4];
  #pragma unroll
  for (int i = 0; i < 4; i++)
    #pragma unroll
    for (int j = 0; j < 4; j++) acc[i][j] = (f32x4){0.f, 0.f, 0.f, 0.f};

  LOADT(0);
  STORET();
  LOADT(1);
  __syncthreads();

  const int swzA = 8 * (lrow & 7);
  for (int kt = 0; kt < 4; ++kt) {
    f16x8 a[4][2], bf[4][2];
    #pragma unroll
    for (int i = 0; i < 4; i++) {
      const int ra = (wm * 64 + i * 16 + lrow) * 64;
      a[i][0] = *(const f16x8*)&Xs[ra + ((kg * 8) ^ swzA)];
      a[i][1] = *(const f16x8*)&Xs[ra + ((32 + kg * 8) ^ swzA)];
      const int rb = (wn * 64 + i * 16 + lrow) * 64;
      bf[i][0] = *(const f16x8*)&Ws[rb + ((kg * 8) ^ swzA)];
      bf[i][1] = *(const f16x8*)&Ws[rb + ((32 + kg * 8) ^ swzA)];
    }
    if (mz == 2) {
      #pragma unroll
      for (int i = 0; i < 4; i++)
        #pragma unroll
        for (int j = 0; j < 4; j++) {
          acc[i][j] = __builtin_amdgcn_mfma_f32_16x16x32_f16(bf[j][0], a[i][0], acc[i][j], 0, 0, 0);
          acc[i][j] = __builtin_amdgcn_mfma_f32_16x16x32_f16(bf[j][1], a[i][1], acc[i][j], 0, 0, 0);
        }
    } else {
      #pragma unroll
      for (int i = 0; i < 4; i++)
        #pragma unroll
        for (int j = 0; j < 4; j++) {
          acc[i][j] = __builtin_amdgcn_mfma_f32_16x16x32_f16(a[i][0], bf[j][0], acc[i][j], 0, 0, 0);
          acc[i][j] = __builtin_amdgcn_mfma_f32_16x16x32_f16(a[i][1], bf[j][1], acc[i][j], 0, 0, 0);
        }
    }
    if (kt < 3) {
      __syncthreads();
      STORET();
      if (kt < 2) LOADT(kt + 2);
      __syncthreads();
    }
  }

  if (mz == 2) {
    #pragma unroll
    for (int i = 0; i < 4; i++) {
      const int sg = s0 + wm * 64 + i * 16 + lrow;
      #pragma unroll
      for (int j = 0; j < 4; j++) {
        #pragma unroll
        for (int r = 0; r < 4; r++) {
          const int c = c0 + wn * 64 + j * 16 + kg * 4 + r;
          outp[(((size_t)b * NH + (c >> 6)) * DH + (c & 63)) * SS + sg] =
              f2h(acc[i][j][r] + bias[c]);
        }
      }
    }
  } else {
    #pragma unroll
    for (int i = 0; i < 4; i++) {
      const int srw = s0 + wm * 64 + i * 16 + kg * 4;
      #pragma unroll
      for (int j = 0; j < 4; j++) {
        const int cgl = c0 + wn * 64 + j * 16 + lrow;
        const float bias_c = bias[cgl] * bscale;
        const size_t obase = (((size_t)b * NH + (cgl >> 6)) * SS) * DH + (cgl & 63);
        #pragma unroll
        for (int r = 0; r < 4; r++)
          outp[obase + (size_t)(srw + r) * DH] = f2h(acc[i][j][r] + bias_c);
      }
    }
  }
}

// ---------------------------------------------------------------------------
// Kernel 3: causal flash attention (session-best version, rounds 12/15).
// 1024 blocks x 256 threads (4 waves), CU-balanced qt mapping; swapped-
// operand dataflow; in-register P butterfly; reg-staged double-buffered LDS;
// 1 barrier/tile; mx cross-lane reduce inside the rare rescale branch.
// ---------------------------------------------------------------------------
__global__ __launch_bounds__(256, 4)
void attn_kernel(const ushort* __restrict__ Q, const ushort* __restrict__ K,
                 const ushort* __restrict__ V, float* __restrict__ out) {
  const int wg = blockIdx.x;                   // 0..1023
  const int j  = wg >> 3;
  const int r  = j & 15, s = j >> 4;
  const int qt = ((s >> 1) & 1) ? (15 - r) : r;
  const int bh = (wg & 7) * 8 + s;
  const int nt = qt + 1;
  const int t = threadIdx.x;
  const int wave = t >> 6, lane = t & 63;
  const int lrow = lane & 15, kg = lane >> 4;

  __shared__ __align__(16) ushort Ks[2][64 * 64];
  __shared__ __align__(16) ushort Vs[2][64 * 64];

  const ushort* Qb = Q + (size_t)bh * SS * DH;
  const ushort* Kb = K + (size_t)bh * SS * DH;   // [s][d]
  const ushort* Vb = V + (size_t)bh * DH * SS;   // [d][s]

  const int qg = qt * 64 + wave * 16 + lrow;

  f16x8 qa0 = *(const f16x8*)&Qb[(size_t)qg * DH + kg * 8];
  f16x8 qa1 = *(const f16x8*)&Qb[(size_t)qg * DH + 32 + kg * 8];

  float m = -1e30f, l = 0.f;
  f32x4 o[4];
  #pragma unroll
  for (int d = 0; d < 4; d++) o[d] = (f32x4){0.f, 0.f, 0.f, 0.f};

  const int r0 = t >> 3,        c0s = (t & 7) * 8;
  const int r1 = 32 + (t >> 3), c1s = c0s;
  const int ke0 = r0 * 64 + (c0s ^ (8 * (r0 & 7)));
  const int ke1 = r1 * 64 + (c1s ^ (8 * (r1 & 7)));

  f16x8 kr0, kr1, vr0, vr1;
  auto LOADT = [&](int jt) {
    const int j0 = jt * 64;
    kr0 = *(const f16x8*)&Kb[(size_t)(j0 + r0) * DH + c0s];
    kr1 = *(const f16x8*)&Kb[(size_t)(j0 + r1) * DH + c1s];
    vr0 = *(const f16x8*)&Vb[(size_t)r0 * SS + j0 + c0s];
    vr1 = *(const f16x8*)&Vb[(size_t)r1 * SS + j0 + c1s];
  };
  auto STORET = [&](int buf) {
    *(f16x8*)&Ks[buf][ke0] = kr0;
    *(f16x8*)&Ks[buf][ke1] = kr1;
    *(f16x8*)&Vs[buf][ke0] = vr0;
    *(f16x8*)&Vs[buf][ke1] = vr1;
  };

  LOADT(0);
  STORET(0);
  if (nt > 1) LOADT(1);
  __syncthreads();

  const int swz = 8 * (lrow & 7);

  for (int jt = 0; jt < nt; ++jt) {
    const int cur = jt & 1;
    const ushort* Kc = Ks[cur];
    const ushort* Vc = Vs[cur];
    const int j0 = jt * 64;
    const bool diag = (jt == qt);

    // S^T = K·Q^T  (z[cf][r] = score[key j0+cf*16+kg*4+r][q = qg], log2 dom)
    f32x4 z[4];
    #pragma unroll
    for (int cf = 0; cf < 4; cf++) z[cf] = (f32x4){0.f, 0.f, 0.f, 0.f};
    #pragma unroll
    for (int cf = 0; cf < 4; ++cf) {
      const int krow = (cf * 16 + lrow) * 64;
      f16x8 ka0 = *(const f16x8*)&Kc[krow + ((kg * 8) ^ swz)];
      f16x8 ka1 = *(const f16x8*)&Kc[krow + ((32 + kg * 8) ^ swz)];
      z[cf] = __builtin_amdgcn_mfma_f32_16x16x32_f16(ka0, qa0, z[cf], 0, 0, 0);
      z[cf] = __builtin_amdgcn_mfma_f32_16x16x32_f16(ka1, qa1, z[cf], 0, 0, 0);
    }

    if (diag) {
      #pragma unroll
      for (int cf = 0; cf < 4; cf++)
        #pragma unroll
        for (int rr = 0; rr < 4; rr++) {
          const int keyi = j0 + cf * 16 + kg * 4 + rr;
          if (keyi >= qg) z[cf][rr] = -1e9f;
        }
    }
    // lane-local max; full cross-lane reduce only inside the rescale branch
    float mxl = z[0][0];
    #pragma unroll
    for (int cf = 0; cf < 4; cf++)
      #pragma unroll
      for (int rr = 0; rr < 4; rr++) mxl = fmaxf(mxl, z[cf][rr]);
    if (__any(mxl > m + THR)) {
      float mx = fmaxf(mxl, __shfl_xor(mxl, 16));
      mx = fmaxf(mx, __shfl_xor(mx, 32));
      const float mn = fmaxf(m, mx);
      const float corr = exp2f(m - mn);
      m = mn;
      l *= corr;
      #pragma unroll
      for (int d = 0; d < 4; d++) o[d] *= corr;
    }
    float ps = 0.f;
    #pragma unroll
    for (int cf = 0; cf < 4; cf++)
      #pragma unroll
      for (int rr = 0; rr < 4; rr++) {
        z[cf][rr] = exp2f(z[cf][rr] - m);
        ps += z[cf][rr];
      }
    ps += __shfl_xor(ps, 16);
    ps += __shfl_xor(ps, 32);
    l += ps;

    // In-register P redistribution (4-lane kg butterfly).
    uint u0 = pk2u(z[0][0], z[0][1]), u1 = pk2u(z[0][2], z[0][3]);
    uint u2 = pk2u(z[1][0], z[1][1]), u3 = pk2u(z[1][2], z[1][3]);
    uint u4 = pk2u(z[2][0], z[2][1]), u5 = pk2u(z[2][2], z[2][3]);
    uint u6 = pk2u(z[3][0], z[3][1]), u7 = pk2u(z[3][2], z[3][3]);
    const bool hi2 = (kg & 2) != 0;
    uint tA0 = hi2 ? u0 : u2, tA1 = hi2 ? u1 : u3;
    uint tA2 = hi2 ? u4 : u6, tA3 = hi2 ? u5 : u7;
    uint rA0 = __shfl_xor((int)tA0, 32), rA1 = __shfl_xor((int)tA1, 32);
    uint rA2 = __shfl_xor((int)tA2, 32), rA3 = __shfl_xor((int)tA3, 32);
    const bool sel = ((kg ^ (kg >> 1)) & 1) != 0;
    uint oc0 = hi2 ? u2 : u0, oc1 = hi2 ? u3 : u1;
    uint oc2 = hi2 ? u6 : u4, oc3 = hi2 ? u7 : u5;
    uint sB0 = sel ? oc0 : rA0, sB1 = sel ? oc1 : rA1;
    uint sB2 = sel ? oc2 : rA2, sB3 = sel ? oc3 : rA3;
    uint rB0 = __shfl_xor((int)sB0, 16), rB1 = __shfl_xor((int)sB1, 16);
    uint rB2 = __shfl_xor((int)sB2, 16), rB3 = __shfl_xor((int)sB3, 16);
    uint w0 = (kg == 0) ? u0 : ((kg == 2) ? rA0 : rB0);
    uint w1 = (kg == 0) ? u1 : ((kg == 2) ? rA1 : rB1);
    uint w2 = (kg == 3) ? u2 : ((kg == 1) ? rA0 : rB0);
    uint w3 = (kg == 3) ? u3 : ((kg == 1) ? rA1 : rB1);
    uint w4 = (kg == 0) ? u4 : ((kg == 2) ? rA2 : rB2);
    uint w5 = (kg == 0) ? u5 : ((kg == 2) ? rA3 : rB3);
    uint w6 = (kg == 3) ? u6 : ((kg == 1) ? rA2 : rB2);
    uint w7 = (kg == 3) ? u7 : ((kg == 1) ? rA3 : rB3);
    union { u32x4 u; f16x8 h; } pa0v, pa1v;
    pa0v.u = (u32x4){w0, w1, w2, w3};
    pa1v.u = (u32x4){w4, w5, w6, w7};

    // O^T += V^T · P^T
    #pragma unroll
    for (int dt = 0; dt < 4; ++dt) {
      const int vrow = (dt * 16 + lrow) * 64;
      f16x8 va0 = *(const f16x8*)&Vc[vrow + ((kg * 8) ^ swz)];
      f16x8 va1 = *(const f16x8*)&Vc[vrow + ((32 + kg * 8) ^ swz)];
      o[dt] = __builtin_amdgcn_mfma_f32_16x16x32_f16(va0, pa0v.h, o[dt], 0, 0, 0);
      o[dt] = __builtin_amdgcn_mfma_f32_16x16x32_f16(va1, pa1v.h, o[dt], 0, 0, 0);
    }

    if (jt + 1 < nt) {
      STORET(cur ^ 1);
      if (jt + 2 < nt) LOADT(jt + 2);
      __syncthreads();
    }
  }

  const int b = bh >> 3, h = bh & 7;
  float* ob = out + ((size_t)b * CC + h * DH) * SS;
  float inv = (l > 0.f) ? 1.f / l : 0.f;
  if (qg == 0) inv = 0.f;            // start_mask: row 0 has no valid keys
  #pragma unroll
  for (int dt = 0; dt < 4; dt++)
    #pragma unroll
    for (int rr = 0; rr < 4; rr++)
      ob[(size_t)(dt * 16 + kg * 4 + rr) * SS + qg] = o[dt][rr] * inv;
}

// ---------------------------------------------------------------------------
extern "C" void kernel_launch(void* const* d_in, const int* in_sizes, int n_in,
                              void* d_out, int out_size, void* d_ws, size_t ws_size,
                              hipStream_t stream) {
  const float* query = (const float*)d_in[0];
  const float* key   = (const float*)d_in[1];
  const float* vq = (const float*)d_in[2];
  const float* gq = (const float*)d_in[3];
  const float* bq = (const float*)d_in[4];
  const float* vk = (const float*)d_in[5];
  const float* gk = (const float*)d_in[6];
  const float* bk = (const float*)d_in[7];
  const float* vv = (const float*)d_in[8];
  const float* gv = (const float*)d_in[9];
  const float* bv = (const float*)d_in[10];
  float* out = (float*)d_out;

  ushort* w_all = (ushort*)d_ws;                                   // [3][512][256] f16
  ushort* qkv   = w_all + (size_t)3 * CC * CIN;
  ushort* Xt    = qkv + (size_t)3 * NB * NH * SS * DH;             // [2][B][S][K] f16
  ushort* qb  = qkv;
  ushort* kb2 = qkv + (size_t)NB * NH * SS * DH;
  ushort* vb2 = kb2 + (size_t)NB * NH * SS * DH;                   // [b][h][d][s]

  prep_kernel<<<2560, 256, 0, stream>>>(query, key, vq, gq, vk, gk, vv, gv, Xt, w_all);
  proj_kernel<<<768, 256, 0, stream>>>(Xt, w_all, bq, bk, bv, qkv);
  attn_kernel<<<1024, 256, 0, stream>>>(qb, kb2, vb2, out);
}